// Round 1
// baseline (195.091 us; speedup 1.0000x reference)
//
#include <hip/hip_runtime.h>
#include <math.h>

#define NN 256
#define NS 512
#define MS 32
#define NSTEP 32
#define VRESET 1.0f

__device__ __forceinline__ float sigf(float x) {
    // accurate fp32 sigmoid: 1/(1+exp(-x)); expf is ~1 ulp (OCML)
    return 1.0f / (1.0f + expf(-x));
}

// One wave (64 lanes) per sample; lane handles neurons n = lane + 64*j, j=0..3.
__global__ __launch_bounds__(64) void snn_kernel(
    const float* __restrict__ ic_g,     // (256,)
    const float* __restrict__ w,        // (256,256)
    const float* __restrict__ mu,       // (2,)
    const float* __restrict__ v0,       // (256,)
    const float* __restrict__ i0,       // (256,)
    const float* __restrict__ s0,       // (512,256)
    const float* __restrict__ reset_s,  // (32,512,256)
    const int*   __restrict__ t1p,      // scalar
    float* __restrict__ out)
{
    const int lane = threadIdx.x;
    const int samp = blockIdx.x;
    const float mu1 = mu[0];
    const float mu2 = mu[1];
    const float t1f = (float)t1p[0];

    float v[4], ii[4], s[4], ic[4];
#pragma unroll
    for (int j = 0; j < 4; ++j) {
        int n = lane + 64 * j;
        v[j]  = v0[n];
        ii[j] = i0[n];
        s[j]  = s0[samp * NN + n];
        ic[j] = ic_g[n];
    }
    float t0 = 0.0f;

    float* times = out;                                  // [NS][MS]
    float* vals  = out + (size_t)NS * MS;                // [NS][MS][NN][3]
    float* marks = out + (size_t)NS * MS * (1 + NN * 3); // [NS][MS][NN]

    for (int r = 0; r < MS; ++r) {
        const float dt = (t1f - t0) / (float)NSTEP;
        float tev = t1f;
        float yev_v[4], yev_i[4], yev_s[4];
        bool  em[4];
        bool  done = false;

        if (dt != 0.0f) {
            float t = t0;
            for (int st = 0; st < NSTEP; ++st) {
                float vn[4], inw[4], sn[4];
#pragma unroll
                for (int j = 0; j < 4; ++j) {
                    float kv1 = mu1 * (ii[j] + ic[j] - v[j]);
                    float ki1 = -mu2 * ii[j];
                    float ks1 = sigf(v[j]);
                    float v2 = v[j] + 0.5f * dt * kv1;
                    float i2 = ii[j] + 0.5f * dt * ki1;
                    float kv2 = mu1 * (i2 + ic[j] - v2);
                    float ki2 = -mu2 * i2;
                    float ks2 = sigf(v2);
                    float v3 = v[j] + 0.5f * dt * kv2;
                    float i3 = ii[j] + 0.5f * dt * ki2;
                    float kv3 = mu1 * (i3 + ic[j] - v3);
                    float ki3 = -mu2 * i3;
                    float ks3 = sigf(v3);
                    float v4 = v[j] + dt * kv3;
                    float i4 = ii[j] + dt * ki3;
                    float kv4 = mu1 * (i4 + ic[j] - v4);
                    float ki4 = -mu2 * i4;
                    float ks4 = sigf(v4);
                    float h6 = dt * (1.0f / 6.0f);
                    vn[j]  = v[j]  + h6 * (kv1 + 2.0f * kv2 + 2.0f * kv3 + kv4);
                    inw[j] = ii[j] + h6 * (ki1 + 2.0f * ki2 + 2.0f * ki3 + ki4);
                    sn[j]  = s[j]  + h6 * (ks1 + 2.0f * ks2 + 2.0f * ks3 + ks4);
                }
                // wave-wide argmax of sn over 256 neurons, carrying s_prev.
                // Order: larger value wins; tie -> smaller neuron index
                // (matches jnp.argmax first-max semantics).
                float bv = sn[0], bsp = s[0];
                int   bn = lane;
#pragma unroll
                for (int j = 1; j < 4; ++j) {
                    if (sn[j] > bv) { bv = sn[j]; bsp = s[j]; bn = lane + 64 * j; }
                }
#pragma unroll
                for (int off = 32; off >= 1; off >>= 1) {
                    float ov  = __shfl_xor(bv, off);
                    float osp = __shfl_xor(bsp, off);
                    int   on  = __shfl_xor(bn, off);
                    if (ov > bv || (ov == bv && on < bn)) { bv = ov; bsp = osp; bn = on; }
                }
                if (bv > 0.0f) {
                    float frac = bsp / (bsp - bv + 1e-12f);
                    frac = fminf(fmaxf(frac, 0.0f), 1.0f);
                    tev = t + frac * dt;
#pragma unroll
                    for (int j = 0; j < 4; ++j) {
                        yev_v[j] = v[j]  + frac * (vn[j]  - v[j]);
                        yev_i[j] = ii[j] + frac * (inw[j] - ii[j]);
                        yev_s[j] = s[j]  + frac * (sn[j]  - s[j]);
                        em[j] = sn[j] > 0.0f;
                        v[j] = yev_v[j]; ii[j] = yev_i[j]; s[j] = yev_s[j];
                    }
                    done = true;
                    break;
                }
#pragma unroll
                for (int j = 0; j < 4; ++j) { v[j] = vn[j]; ii[j] = inw[j]; s[j] = sn[j]; }
                t += dt;
            }
        }

        if (!done) {
            tev = t1f;
#pragma unroll
            for (int j = 0; j < 4; ++j) {
                yev_v[j] = v[j]; yev_i[j] = ii[j]; yev_s[j] = s[j]; em[j] = false;
            }
        }

        // ---- emit round outputs ----
        const int sr = samp * MS + r;
        if (lane == 0) times[sr] = tev;
#pragma unroll
        for (int j = 0; j < 4; ++j) {
            int n = lane + 64 * j;
            float* p = vals + ((size_t)sr * NN + n) * 3;
            p[0] = yev_v[j];
            p[1] = yev_i[j];
            p[2] = yev_s[j];
            marks[(size_t)sr * NN + n] = em[j] ? 1.0f : 0.0f;
        }

        // ---- reset for next round ----
        if (done) {
            // eidx = smallest neuron index with em true
            int cand = 2 * NN;
#pragma unroll
            for (int j = 3; j >= 0; --j) if (em[j]) cand = lane + 64 * j;
#pragma unroll
            for (int off = 32; off >= 1; off >>= 1) {
                int oc = __shfl_xor(cand, off);
                cand = (oc < cand) ? oc : cand;
            }
            const int eidx = cand;
#pragma unroll
            for (int j = 0; j < 4; ++j) {
                int n = lane + 64 * j;
                float wr = w[eidx * NN + n];
                v[j]  = yev_v[j] - (em[j] ? VRESET : 0.0f);
                ii[j] = yev_i[j] + wr;
                float sres = em[j] ? reset_s[((size_t)r * NS + samp) * NN + n] : yev_s[j];
                s[j] = fminf(sres, 0.0f);
            }
        } else {
            // done==false: w_row = 0, v/i unchanged, s = min(s, 0)
#pragma unroll
            for (int j = 0; j < 4; ++j) s[j] = fminf(s[j], 0.0f);
        }
        t0 = tev;
    }
}

extern "C" void kernel_launch(void* const* d_in, const int* in_sizes, int n_in,
                              void* d_out, int out_size, void* d_ws, size_t ws_size,
                              hipStream_t stream) {
    const float* ic      = (const float*)d_in[0];
    const float* w       = (const float*)d_in[1];
    const float* mu      = (const float*)d_in[2];
    const float* v0      = (const float*)d_in[3];
    const float* i0      = (const float*)d_in[4];
    const float* s0      = (const float*)d_in[5];
    const float* reset_s = (const float*)d_in[6];
    const int*   t1p     = (const int*)d_in[7];
    float* out = (float*)d_out;

    snn_kernel<<<dim3(NS), dim3(64), 0, stream>>>(ic, w, mu, v0, i0, s0,
                                                  reset_s, t1p, out);
}

// Round 2
// 153.863 us; speedup vs baseline: 1.2680x; 1.2680x over previous
//
#include <hip/hip_runtime.h>
#include <math.h>

#define NN 256
#define NS 512
#define MS 32
#define NSTEP 32
#define VRESET 1.0f

__device__ __forceinline__ float sigf(float x) {
    // fast sigmoid: v_exp_f32 (+ mul by log2e inside __expf) + v_rcp_f32.
    // ~3 ulp vs correctly-rounded; event-flip risk analyzed in journal R2.
    float e = __expf(-x);
    return __builtin_amdgcn_rcpf(1.0f + e);
}

// One wave (64 lanes) per sample; lane handles neurons n = lane + 64*j, j=0..3.
__global__ __launch_bounds__(64) void snn_kernel(
    const float* __restrict__ ic_g,     // (256,)
    const float* __restrict__ w,        // (256,256)
    const float* __restrict__ mu,       // (2,)
    const float* __restrict__ v0,       // (256,)
    const float* __restrict__ i0,       // (256,)
    const float* __restrict__ s0,       // (512,256)
    const float* __restrict__ reset_s,  // (32,512,256)
    const int*   __restrict__ t1p,      // scalar
    float* __restrict__ out)
{
    const int lane = threadIdx.x;
    const int samp = blockIdx.x;
    const float mu1 = mu[0];
    const float mu2 = mu[1];
    const float t1f = (float)t1p[0];

    float v[4], ii[4], s[4], ic[4];
#pragma unroll
    for (int j = 0; j < 4; ++j) {
        int n = lane + 64 * j;
        v[j]  = v0[n];
        ii[j] = i0[n];
        s[j]  = s0[samp * NN + n];
        ic[j] = ic_g[n];
    }
    float t0 = 0.0f;

    float* times = out;                                  // [NS][MS]
    float* vals  = out + (size_t)NS * MS;                // [NS][MS][NN][3]
    float* marks = out + (size_t)NS * MS * (1 + NN * 3); // [NS][MS][NN]

    for (int r = 0; r < MS; ++r) {
        const float dt = (t1f - t0) / (float)NSTEP;
        float tev = t1f;
        float yev_v[4], yev_i[4], yev_s[4];
        bool  em[4];
        bool  done = false;

        if (dt != 0.0f) {
            float t = t0;
            const float hh = 0.5f * dt;
            const float h6 = dt * (1.0f / 6.0f);
            for (int st = 0; st < NSTEP; ++st) {
                float vn[4], inw[4], sn[4];
#pragma unroll
                for (int j = 0; j < 4; ++j) {
                    float kv1 = mu1 * (ii[j] + ic[j] - v[j]);
                    float ki1 = -mu2 * ii[j];
                    float ks1 = sigf(v[j]);
                    float v2 = v[j] + hh * kv1;
                    float i2 = ii[j] + hh * ki1;
                    float kv2 = mu1 * (i2 + ic[j] - v2);
                    float ki2 = -mu2 * i2;
                    float ks2 = sigf(v2);
                    float v3 = v[j] + hh * kv2;
                    float i3 = ii[j] + hh * ki2;
                    float kv3 = mu1 * (i3 + ic[j] - v3);
                    float ki3 = -mu2 * i3;
                    float ks3 = sigf(v3);
                    float v4 = v[j] + dt * kv3;
                    float i4 = ii[j] + dt * ki3;
                    float kv4 = mu1 * (i4 + ic[j] - v4);
                    float ki4 = -mu2 * i4;
                    float ks4 = sigf(v4);
                    vn[j]  = v[j]  + h6 * (kv1 + 2.0f * kv2 + 2.0f * kv3 + kv4);
                    inw[j] = ii[j] + h6 * (ki1 + 2.0f * ki2 + 2.0f * ki3 + ki4);
                    sn[j]  = s[j]  + h6 * (ks1 + 2.0f * ks2 + 2.0f * ks3 + ks4);
                }
                // Cheap common-path test: did ANY of the 256 neurons cross?
                // (a crossing happens at most once per round, so the expensive
                // argmax is off the per-step critical path)
                bool any4 = (sn[0] > 0.0f) | (sn[1] > 0.0f) |
                            (sn[2] > 0.0f) | (sn[3] > 0.0f);
                if (__any(any4)) {
                    // wave-wide argmax of sn over 256 neurons, carrying s_prev.
                    // Larger value wins; tie -> smaller neuron index
                    // (matches jnp.argmax first-max semantics).
                    float bv = sn[0], bsp = s[0];
                    int   bn = lane;
#pragma unroll
                    for (int j = 1; j < 4; ++j) {
                        if (sn[j] > bv) { bv = sn[j]; bsp = s[j]; bn = lane + 64 * j; }
                    }
#pragma unroll
                    for (int off = 32; off >= 1; off >>= 1) {
                        float ov  = __shfl_xor(bv, off);
                        float osp = __shfl_xor(bsp, off);
                        int   on  = __shfl_xor(bn, off);
                        if (ov > bv || (ov == bv && on < bn)) { bv = ov; bsp = osp; bn = on; }
                    }
                    float frac = bsp / (bsp - bv + 1e-12f);
                    frac = fminf(fmaxf(frac, 0.0f), 1.0f);
                    tev = t + frac * dt;
#pragma unroll
                    for (int j = 0; j < 4; ++j) {
                        yev_v[j] = v[j]  + frac * (vn[j]  - v[j]);
                        yev_i[j] = ii[j] + frac * (inw[j] - ii[j]);
                        yev_s[j] = s[j]  + frac * (sn[j]  - s[j]);
                        em[j] = sn[j] > 0.0f;
                        v[j] = yev_v[j]; ii[j] = yev_i[j]; s[j] = yev_s[j];
                    }
                    done = true;
                    break;
                }
#pragma unroll
                for (int j = 0; j < 4; ++j) { v[j] = vn[j]; ii[j] = inw[j]; s[j] = sn[j]; }
                t += dt;
            }
        }

        if (!done) {
            tev = t1f;
#pragma unroll
            for (int j = 0; j < 4; ++j) {
                yev_v[j] = v[j]; yev_i[j] = ii[j]; yev_s[j] = s[j]; em[j] = false;
            }
        }

        // ---- emit round outputs ----
        const int sr = samp * MS + r;
        if (lane == 0) times[sr] = tev;
#pragma unroll
        for (int j = 0; j < 4; ++j) {
            int n = lane + 64 * j;
            float* p = vals + ((size_t)sr * NN + n) * 3;
            p[0] = yev_v[j];
            p[1] = yev_i[j];
            p[2] = yev_s[j];
            marks[(size_t)sr * NN + n] = em[j] ? 1.0f : 0.0f;
        }

        // ---- reset for next round ----
        if (done) {
            // eidx = smallest neuron index with em true
            int cand = 2 * NN;
#pragma unroll
            for (int j = 3; j >= 0; --j) if (em[j]) cand = lane + 64 * j;
#pragma unroll
            for (int off = 32; off >= 1; off >>= 1) {
                int oc = __shfl_xor(cand, off);
                cand = (oc < cand) ? oc : cand;
            }
            const int eidx = cand;
#pragma unroll
            for (int j = 0; j < 4; ++j) {
                int n = lane + 64 * j;
                float wr = w[eidx * NN + n];
                v[j]  = yev_v[j] - (em[j] ? VRESET : 0.0f);
                ii[j] = yev_i[j] + wr;
                float sres = em[j] ? reset_s[((size_t)r * NS + samp) * NN + n] : yev_s[j];
                s[j] = fminf(sres, 0.0f);
            }
        } else {
            // done==false: w_row = 0, v/i unchanged, s = min(s, 0)
#pragma unroll
            for (int j = 0; j < 4; ++j) s[j] = fminf(s[j], 0.0f);
        }
        t0 = tev;
    }
}

extern "C" void kernel_launch(void* const* d_in, const int* in_sizes, int n_in,
                              void* d_out, int out_size, void* d_ws, size_t ws_size,
                              hipStream_t stream) {
    const float* ic      = (const float*)d_in[0];
    const float* w       = (const float*)d_in[1];
    const float* mu      = (const float*)d_in[2];
    const float* v0      = (const float*)d_in[3];
    const float* i0      = (const float*)d_in[4];
    const float* s0      = (const float*)d_in[5];
    const float* reset_s = (const float*)d_in[6];
    const int*   t1p     = (const int*)d_in[7];
    float* out = (float*)d_out;

    snn_kernel<<<dim3(NS), dim3(64), 0, stream>>>(ic, w, mu, v0, i0, s0,
                                                  reset_s, t1p, out);
}

// Round 3
// 153.014 us; speedup vs baseline: 1.2750x; 1.0056x over previous
//
#include <hip/hip_runtime.h>
#include <math.h>

#define NN 256
#define NS 512
#define MS 32
#define NSTEP 32
#define VRESET 1.0f

__device__ __forceinline__ float sigf(float x) {
    // fast sigmoid: v_exp_f32 + v_rcp_f32 (~3 ulp); verified no event flips
    // (absmax identical to OCML expf version: 0.125).
    float e = __expf(-x);
    return __builtin_amdgcn_rcpf(1.0f + e);
}

// One block (256 threads = 4 waves) per sample; thread tid owns neuron tid.
// Arithmetic is op-for-op identical to the R2 kernel (bitwise-same outputs);
// only the work distribution changed (4 neurons/lane -> 1 neuron/lane).
__global__ __launch_bounds__(256) void snn_kernel(
    const float* __restrict__ ic_g,     // (256,)
    const float* __restrict__ w,        // (256,256)
    const float* __restrict__ mu,       // (2,)
    const float* __restrict__ v0,       // (256,)
    const float* __restrict__ i0,       // (256,)
    const float* __restrict__ s0,       // (512,256)
    const float* __restrict__ reset_s,  // (32,512,256)
    const int*   __restrict__ t1p,      // scalar
    float* __restrict__ out)
{
    const int tid  = threadIdx.x;   // neuron index
    const int lane = tid & 63;
    const int wid  = tid >> 6;
    const int samp = blockIdx.x;
    const float mu1 = mu[0];
    const float mu2 = mu[1];
    const float t1f = (float)t1p[0];

    __shared__ int   s_any[2][4];   // per-step crossing flag, parity dbuf
    __shared__ float s_bv[4], s_bsp[4];
    __shared__ int   s_bn[4];
    __shared__ int   s_eidx[4];

    float v  = v0[tid];
    float ii = i0[tid];
    float s  = s0[samp * NN + tid];
    const float ic = ic_g[tid];
    float t0 = 0.0f;

    float* times = out;                                  // [NS][MS]
    float* vals  = out + (size_t)NS * MS;                // [NS][MS][NN][3]
    float* marks = out + (size_t)NS * MS * (1 + NN * 3); // [NS][MS][NN]

    for (int r = 0; r < MS; ++r) {
        const float dt = (t1f - t0) / (float)NSTEP;
        float tev = t1f;
        float yev_v, yev_i, yev_s;
        bool  em = false;
        bool  done = false;

        if (dt != 0.0f) {
            float t = t0;
            const float hh = 0.5f * dt;
            const float h6 = dt * (1.0f / 6.0f);
            for (int st = 0; st < NSTEP; ++st) {
                // RK4 (identical op order to previous kernel)
                float kv1 = mu1 * (ii + ic - v);
                float ki1 = -mu2 * ii;
                float ks1 = sigf(v);
                float v2 = v + hh * kv1;
                float i2 = ii + hh * ki1;
                float kv2 = mu1 * (i2 + ic - v2);
                float ki2 = -mu2 * i2;
                float ks2 = sigf(v2);
                float v3 = v + hh * kv2;
                float i3 = ii + hh * ki2;
                float kv3 = mu1 * (i3 + ic - v3);
                float ki3 = -mu2 * i3;
                float ks3 = sigf(v3);
                float v4 = v + dt * kv3;
                float i4 = ii + dt * ki3;
                float kv4 = mu1 * (i4 + ic - v4);
                float ki4 = -mu2 * i4;
                float ks4 = sigf(v4);
                float vn = v  + h6 * (kv1 + 2.0f * kv2 + 2.0f * kv3 + kv4);
                float in_ = ii + h6 * (ki1 + 2.0f * ki2 + 2.0f * ki3 + ki4);
                float sn = s  + h6 * (ks1 + 2.0f * ks2 + 2.0f * ks3 + ks4);

                // block-wide "any crossed?" — wave ballot + 4-slot LDS OR.
                // parity double-buffer -> single barrier per step, no WAR.
                unsigned long long bl = __ballot(sn > 0.0f);
                if (lane == 0) s_any[st & 1][wid] = (bl != 0ull) ? 1 : 0;
                __syncthreads();
                int anyflag = s_any[st & 1][0] | s_any[st & 1][1] |
                              s_any[st & 1][2] | s_any[st & 1][3];

                if (anyflag) {
                    // block-wide argmax of sn (value desc, index asc tie-break),
                    // carrying s_prev. Same semantics as before.
                    float bv = sn, bsp = s;
                    int   bn = tid;
#pragma unroll
                    for (int off = 32; off >= 1; off >>= 1) {
                        float ov  = __shfl_xor(bv, off);
                        float osp = __shfl_xor(bsp, off);
                        int   on  = __shfl_xor(bn, off);
                        if (ov > bv || (ov == bv && on < bn)) { bv = ov; bsp = osp; bn = on; }
                    }
                    if (lane == 0) { s_bv[wid] = bv; s_bsp[wid] = bsp; s_bn[wid] = bn; }
                    __syncthreads();
                    bv = s_bv[0]; bsp = s_bsp[0]; bn = s_bn[0];
#pragma unroll
                    for (int wv = 1; wv < 4; ++wv) {
                        float ov = s_bv[wv], osp = s_bsp[wv];
                        int   on = s_bn[wv];
                        if (ov > bv || (ov == bv && on < bn)) { bv = ov; bsp = osp; bn = on; }
                    }
                    float frac = bsp / (bsp - bv + 1e-12f);
                    frac = fminf(fmaxf(frac, 0.0f), 1.0f);
                    tev = t + frac * dt;
                    yev_v = v  + frac * (vn - v);
                    yev_i = ii + frac * (in_ - ii);
                    yev_s = s  + frac * (sn - s);
                    em = sn > 0.0f;
                    v = yev_v; ii = yev_i; s = yev_s;
                    done = true;
                    break;
                }
                v = vn; ii = in_; s = sn;
                t += dt;
            }
        }

        if (!done) {
            tev = t1f;
            yev_v = v; yev_i = ii; yev_s = s; em = false;
        }

        // ---- emit round outputs ----
        const int sr = samp * MS + r;
        if (tid == 0) times[sr] = tev;
        {
            float* p = vals + ((size_t)sr * NN + tid) * 3;
            p[0] = yev_v;
            p[1] = yev_i;
            p[2] = yev_s;
            marks[(size_t)sr * NN + tid] = em ? 1.0f : 0.0f;
        }

        // ---- reset for next round ----
        if (done) {
            // eidx = smallest neuron index with em true
            unsigned long long bm = __ballot(em);
            int cand = (bm != 0ull) ? (wid * 64 + (int)__builtin_ctzll(bm)) : (2 * NN);
            if (lane == 0) s_eidx[wid] = cand;
            __syncthreads();
            int eidx = s_eidx[0];
            eidx = (s_eidx[1] < eidx) ? s_eidx[1] : eidx;
            eidx = (s_eidx[2] < eidx) ? s_eidx[2] : eidx;
            eidx = (s_eidx[3] < eidx) ? s_eidx[3] : eidx;

            float wr = w[eidx * NN + tid];
            v  = yev_v - (em ? VRESET : 0.0f);
            ii = yev_i + wr;
            float sres = em ? reset_s[((size_t)r * NS + samp) * NN + tid] : yev_s;
            s = fminf(sres, 0.0f);
        } else {
            s = fminf(s, 0.0f);
        }
        t0 = tev;
    }
}

extern "C" void kernel_launch(void* const* d_in, const int* in_sizes, int n_in,
                              void* d_out, int out_size, void* d_ws, size_t ws_size,
                              hipStream_t stream) {
    const float* ic      = (const float*)d_in[0];
    const float* w       = (const float*)d_in[1];
    const float* mu      = (const float*)d_in[2];
    const float* v0      = (const float*)d_in[3];
    const float* i0      = (const float*)d_in[4];
    const float* s0      = (const float*)d_in[5];
    const float* reset_s = (const float*)d_in[6];
    const int*   t1p     = (const int*)d_in[7];
    float* out = (float*)d_out;

    snn_kernel<<<dim3(NS), dim3(256), 0, stream>>>(ic, w, mu, v0, i0, s0,
                                                   reset_s, t1p, out);
}